// Round 14
// baseline (340.504 us; speedup 1.0000x reference)
//
#include <hip/hip_runtime.h>
#include <hip/hip_fp16.h>

// GraphSAGE 3-layer forward, f32 output.
// CSR build: 6-kernel chain + folded-in counting sort of nodes by degree
// (perm) so gather waves span same-degree nodes (kills the E[max-of-5.3]
// ~1.4x divergence waste). Gather: thread-per-(perm-node,octet), 4x edge
// unroll, fp16->fp16. GEMM: direct fp16 MFMA, full weight panel in LDS;
// h-planes fp16-only (in-place rotating); final layer writes f32.

#define DIN 96

typedef __attribute__((ext_vector_type(8))) _Float16 f16x8;
typedef __attribute__((ext_vector_type(16))) float f32x16;

// ---- zero fill (deg + bins) ----
__global__ void zero_deg_kernel(int* __restrict__ p, int n) {
    int i = blockIdx.x * blockDim.x + threadIdx.x;
    if (i < n) p[i] = 0;
}

// ---- degree histogram + per-edge rank ----
__global__ void deg_kernel(const int* __restrict__ dst, int* __restrict__ deg,
                           int* __restrict__ rank, int nE) {
    int i = blockIdx.x * blockDim.x + threadIdx.x;
    if (i < nE) rank[i] = atomicAdd(&deg[dst[i]], 1);
}

// ---- scan phase 1: per-block sums + degree-bin histogram ----
__global__ void block_sum_kernel(const int* __restrict__ deg, int* __restrict__ bsum,
                                 int* __restrict__ bins, int nN) {
    __shared__ int s[256];
    __shared__ int lbins[64];
    const int tid = threadIdx.x;
    if (tid < 64) lbins[tid] = 0;
    int i = blockIdx.x * 256 + tid;
    int v = (i < nN) ? deg[i] : 0;
    s[tid] = v;
    __syncthreads();
    if (i < nN) atomicAdd(&lbins[min(v, 63)], 1);
    for (int d = 128; d > 0; d >>= 1) {
        if (tid < d) s[tid] += s[tid + d];
        __syncthreads();
    }
    if (tid == 0) bsum[blockIdx.x] = s[0];
    if (tid < 64 && lbins[tid]) atomicAdd(&bins[tid], lbins[tid]);
}

// ---- scan phase 2: exclusive scan of block sums + of degree bins ----
__global__ void bsum_scan_kernel(int* __restrict__ bsum, int nB,
                                 const int* __restrict__ bins, int* __restrict__ binCur) {
    __shared__ int s[256];
    const int tid = threadIdx.x;
    int v = (tid < nB) ? bsum[tid] : 0;
    s[tid] = v;
    __syncthreads();
    for (int d = 1; d < 256; d <<= 1) {
        int t = (tid >= d) ? s[tid - d] : 0;
        __syncthreads();
        s[tid] += t;
        __syncthreads();
    }
    if (tid < nB) bsum[tid] = s[tid] - v;   // exclusive
    __syncthreads();
    // exclusive scan of 64 degree bins -> binCur
    int bv = (tid < 64) ? bins[tid] : 0;
    s[tid] = bv;
    __syncthreads();
    for (int d = 1; d < 64; d <<= 1) {
        int t = (tid >= d && tid < 64) ? s[tid - d] : 0;
        __syncthreads();
        if (tid < 64) s[tid] += t;
        __syncthreads();
    }
    if (tid < 64) binCur[tid] = s[tid] - bv;
}

// ---- scan phase 3: offs + degree-sorted perm fill ----
__global__ void scan_apply_kernel(const int* __restrict__ deg, const int* __restrict__ bsum,
                                  int* __restrict__ offs, int* __restrict__ binCur,
                                  int* __restrict__ perm, int nN) {
    __shared__ int s[256];
    const int tid = threadIdx.x;
    int i = blockIdx.x * 256 + tid;
    int v = (i < nN) ? deg[i] : 0;
    s[tid] = v;
    __syncthreads();
    for (int d = 1; d < 256; d <<= 1) {
        int t = (tid >= d) ? s[tid - d] : 0;
        __syncthreads();
        s[tid] += t;
        __syncthreads();
    }
    if (i < nN) {
        offs[i] = bsum[blockIdx.x] + s[tid] - v;
        int pos = atomicAdd(&binCur[min(v, 63)], 1);
        perm[pos] = i;
    }
}

// ---- bucket fill (atomic-free) ----
__global__ void bucket_kernel(const int* __restrict__ src, const int* __restrict__ dst,
                              const int* __restrict__ offs, const int* __restrict__ rank,
                              unsigned short* __restrict__ esrc, int nE) {
    int e = blockIdx.x * blockDim.x + threadIdx.x;
    if (e < nE) esrc[offs[dst[e]] + rank[e]] = (unsigned short)src[e];
}

// ---- f32 -> fp16 plane (layer-0 input) ----
__global__ void tof16_kernel(const float* __restrict__ x, __half* __restrict__ xf, int n8) {
    int i = blockIdx.x * blockDim.x + threadIdx.x;
    if (i >= n8) return;
    float4 f0 = *reinterpret_cast<const float4*>(x + (size_t)i * 8);
    float4 f1 = *reinterpret_cast<const float4*>(x + (size_t)i * 8 + 4);
    union { __half2 h2[4]; float4 raw; } o;
    o.h2[0] = __float22half2_rn(make_float2(f0.x, f0.y));
    o.h2[1] = __float22half2_rn(make_float2(f0.z, f0.w));
    o.h2[2] = __float22half2_rn(make_float2(f1.x, f1.y));
    o.h2[3] = __float22half2_rn(make_float2(f1.z, f1.w));
    *reinterpret_cast<float4*>(xf + (size_t)i * 8) = o.raw;
}

// ---- gather: thread = (degree-sorted node, octet); 12 threads/node ----
__global__ void gather_kernel(const __half* __restrict__ hf, const unsigned short* __restrict__ esrc,
                              const int* __restrict__ offs, const int* __restrict__ deg,
                              const int* __restrict__ perm,
                              __half* __restrict__ hmean, int nN) {
    int idx = blockIdx.x * blockDim.x + threadIdx.x;
    if (idx >= nN * 12) return;
    int n = perm[idx / 12];
    int q = idx - (idx / 12) * 12;
    const int beg = offs[n];
    const int dg = deg[n];
    const int end = beg + dg;
    const __half* hq = hf + q * 8;

    union H8 { float4 raw; __half2 h2[4]; };
    float a0[8], a1[8], a2[8], a3[8];
#pragma unroll
    for (int k = 0; k < 8; ++k) { a0[k] = 0.f; a1[k] = 0.f; a2[k] = 0.f; a3[k] = 0.f; }

    int j = beg;
    for (; j + 4 <= end; j += 4) {
        int s0 = esrc[j], s1 = esrc[j + 1], s2 = esrc[j + 2], s3 = esrc[j + 3];
        H8 v0, v1, v2, v3;
        v0.raw = *reinterpret_cast<const float4*>(hq + (size_t)s0 * DIN);
        v1.raw = *reinterpret_cast<const float4*>(hq + (size_t)s1 * DIN);
        v2.raw = *reinterpret_cast<const float4*>(hq + (size_t)s2 * DIN);
        v3.raw = *reinterpret_cast<const float4*>(hq + (size_t)s3 * DIN);
#pragma unroll
        for (int k = 0; k < 4; ++k) {
            float2 f0 = __half22float2(v0.h2[k]);
            float2 f1 = __half22float2(v1.h2[k]);
            float2 f2 = __half22float2(v2.h2[k]);
            float2 f3 = __half22float2(v3.h2[k]);
            a0[2 * k] += f0.x; a0[2 * k + 1] += f0.y;
            a1[2 * k] += f1.x; a1[2 * k + 1] += f1.y;
            a2[2 * k] += f2.x; a2[2 * k + 1] += f2.y;
            a3[2 * k] += f3.x; a3[2 * k + 1] += f3.y;
        }
    }
    for (; j < end; ++j) {
        int s0 = esrc[j];
        H8 v0;
        v0.raw = *reinterpret_cast<const float4*>(hq + (size_t)s0 * DIN);
#pragma unroll
        for (int k = 0; k < 4; ++k) {
            float2 f0 = __half22float2(v0.h2[k]);
            a0[2 * k] += f0.x; a0[2 * k + 1] += f0.y;
        }
    }
    const float r = 1.0f / (float)max(dg, 1);
    union H8 o;
    o.h2[0] = __float22half2_rn(make_float2((a0[0]+a1[0]+a2[0]+a3[0])*r, (a0[1]+a1[1]+a2[1]+a3[1])*r));
    o.h2[1] = __float22half2_rn(make_float2((a0[2]+a1[2]+a2[2]+a3[2])*r, (a0[3]+a1[3]+a2[3]+a3[3])*r));
    o.h2[2] = __float22half2_rn(make_float2((a0[4]+a1[4]+a2[4]+a3[4])*r, (a0[5]+a1[5]+a2[5]+a3[5])*r));
    o.h2[3] = __float22half2_rn(make_float2((a0[6]+a1[6]+a2[6]+a3[6])*r, (a0[7]+a1[7]+a2[7]+a3[7])*r));
    *reinterpret_cast<float4*>(hmean + (size_t)n * DIN + q * 8) = o.raw;
}

// ---- fused SAGE layer GEMM: direct fp16 MFMA ----
template<int DOUT, int NP, bool RELU, bool FINAL>
__global__ __launch_bounds__(256)
void sage_gemm_mfma(const __half* __restrict__ hp, const __half* __restrict__ hm,
                    const float* __restrict__ wself, const float* __restrict__ wneigh,
                    const float* __restrict__ bias, float* __restrict__ fout,
                    __half* __restrict__ hout, int nN) {
    __shared__ unsigned int WS[DOUT][100];   // 200 fp16 per row (192 + pad)

    const int tid = threadIdx.x;
    const int n0 = blockIdx.x * 256;

    for (int c = tid; c < DOUT * 24; c += 256) {
        int r = c / 24, k8 = c - (c / 24) * 24;
        const float* srcw = (k8 < 12) ? (wself + (size_t)r * 96 + k8 * 8)
                                      : (wneigh + (size_t)r * 96 + (k8 - 12) * 8);
        float4 f0 = *reinterpret_cast<const float4*>(srcw);
        float4 f1 = *reinterpret_cast<const float4*>(srcw + 4);
        union { __half2 h2[4]; unsigned int u[4]; } o;
        o.h2[0] = __float22half2_rn(make_float2(f0.x, f0.y));
        o.h2[1] = __float22half2_rn(make_float2(f0.z, f0.w));
        o.h2[2] = __float22half2_rn(make_float2(f1.x, f1.y));
        o.h2[3] = __float22half2_rn(make_float2(f1.z, f1.w));
        WS[r][k8 * 4 + 0] = o.u[0];
        WS[r][k8 * 4 + 1] = o.u[1];
        WS[r][k8 * 4 + 2] = o.u[2];
        WS[r][k8 * 4 + 3] = o.u[3];
    }
    __syncthreads();

    const int lane = tid & 63;
    const int w = tid >> 6;
    const int col = lane & 31;
    const int q = lane >> 5;
    const int mbase = n0 + w * 64;

    const int nA0 = min(mbase + col, nN - 1);
    const int nA1 = min(mbase + 32 + col, nN - 1);

    f32x16 acc[NP][2];
#pragma unroll
    for (int p = 0; p < NP; ++p) {
        f32x16 z = {};
        acc[p][0] = z;
        acc[p][1] = z;
    }

#pragma unroll
    for (int ks = 0; ks < 12; ++ks) {
        const __half* s0 = (ks < 6) ? (hp + (size_t)nA0 * 96 + ks * 16 + q * 8)
                                    : (hm + (size_t)nA0 * 96 + (ks - 6) * 16 + q * 8);
        const __half* s1 = (ks < 6) ? (hp + (size_t)nA1 * 96 + ks * 16 + q * 8)
                                    : (hm + (size_t)nA1 * 96 + (ks - 6) * 16 + q * 8);
        union { float4 raw; f16x8 v; } a0, a1;
        a0.raw = *reinterpret_cast<const float4*>(s0);
        a1.raw = *reinterpret_cast<const float4*>(s1);

#pragma unroll
        for (int p = 0; p < NP; ++p) {
            const f16x8 wv = *reinterpret_cast<const f16x8*>(&WS[p * 32 + col][ks * 8 + q * 4]);
            acc[p][0] = __builtin_amdgcn_mfma_f32_32x32x16_f16(a0.v, wv, acc[p][0], 0, 0, 0);
            acc[p][1] = __builtin_amdgcn_mfma_f32_32x32x16_f16(a1.v, wv, acc[p][1], 0, 0, 0);
        }
    }

    // epilogue: C/D layout col=lane&31, row=(i&3)+8*(i>>2)+4*q
#pragma unroll
    for (int p = 0; p < NP; ++p) {
        const int oc = p * 32 + col;
        const float bv = bias[oc];
#pragma unroll
        for (int i = 0; i < 16; ++i) {
            const int row = (i & 3) + 8 * (i >> 2) + 4 * q;
            int n = mbase + row;
            if (n < nN) {
                float v = acc[p][0][i] + bv;
                if (RELU) v = fmaxf(v, 0.f);
                if (FINAL) fout[(size_t)n * DOUT + oc] = v;
                else       hout[(size_t)n * DOUT + oc] = __float2half_rn(v);
            }
            n = mbase + 32 + row;
            if (n < nN) {
                float v = acc[p][1][i] + bv;
                if (RELU) v = fmaxf(v, 0.f);
                if (FINAL) fout[(size_t)n * DOUT + oc] = v;
                else       hout[(size_t)n * DOUT + oc] = __float2half_rn(v);
            }
        }
    }
}

extern "C" void kernel_launch(void* const* d_in, const int* in_sizes, int n_in,
                              void* d_out, int out_size, void* d_ws, size_t ws_size,
                              hipStream_t stream) {
    const float* x   = (const float*)d_in[0];
    const int*   src = (const int*)d_in[1];
    const int*   dst = (const int*)d_in[2];
    const float* ws0 = (const float*)d_in[3];
    const float* wn0 = (const float*)d_in[4];
    const float* b0  = (const float*)d_in[5];
    const float* ws1 = (const float*)d_in[6];
    const float* wn1 = (const float*)d_in[7];
    const float* b1  = (const float*)d_in[8];
    const float* ws2 = (const float*)d_in[9];
    const float* wn2 = (const float*)d_in[10];
    const float* b2  = (const float*)d_in[11];
    float* out = (float*)d_out;

    const int nN = in_sizes[0] / DIN;   // 50000
    const int nE = in_sizes[1];         // 800000
    const int nB = (nN + 255) / 256;    // scan blocks

    // workspace layout (ints unless noted):
    // deg[50048] bins[64] binCur[64] offs[50048] bsum[256] rank[nE] perm[50048]
    // | esrc[nE] (ushort) | hp16[nN*96] (f16) | hm16[nN*96] (f16)
    int* deg    = (int*)d_ws;
    int* bins   = deg + 50048;
    int* binCur = bins + 64;
    int* offs   = binCur + 64;
    int* bsum   = offs + 50048;
    int* rank   = bsum + 256;
    int* perm   = rank + nE;
    unsigned short* esrc = (unsigned short*)(perm + 50048);
    __half* hp16 = (__half*)(esrc + nE);       // rotating h plane (in-place)
    __half* hm16 = hp16 + (size_t)nN * DIN;    // gather output

    // ---- build CSR by dst + degree-sorted perm ----
    zero_deg_kernel<<<(nN + 64 + 255) / 256, 256, 0, stream>>>(deg, nN + 64 + 64);
    deg_kernel<<<(nE + 255) / 256, 256, 0, stream>>>(dst, deg, rank, nE);
    block_sum_kernel<<<nB, 256, 0, stream>>>(deg, bsum, bins, nN);
    bsum_scan_kernel<<<1, 256, 0, stream>>>(bsum, nB, bins, binCur);
    scan_apply_kernel<<<nB, 256, 0, stream>>>(deg, bsum, offs, binCur, perm, nN);
    bucket_kernel<<<(nE + 255) / 256, 256, 0, stream>>>(src, dst, offs, rank, esrc, nE);

    const int cgrid = (nN * 12 + 255) / 256;
    const int ggrid = (nN * 12 + 255) / 256;
    const int mgrid = (nN + 255) / 256;    // 196 GEMM blocks

    // ---- layer 0 ----
    tof16_kernel<<<cgrid, 256, 0, stream>>>(x, hp16, nN * 12);
    gather_kernel<<<ggrid, 256, 0, stream>>>(hp16, esrc, offs, deg, perm, hm16, nN);
    sage_gemm_mfma<96, 3, true, false><<<mgrid, 256, 0, stream>>>(hp16, hm16, ws0, wn0, b0, nullptr, hp16, nN);

    // ---- layer 1 ----
    gather_kernel<<<ggrid, 256, 0, stream>>>(hp16, esrc, offs, deg, perm, hm16, nN);
    sage_gemm_mfma<96, 3, true, false><<<mgrid, 256, 0, stream>>>(hp16, hm16, ws1, wn1, b1, nullptr, hp16, nN);

    // ---- layer 2 ----
    gather_kernel<<<ggrid, 256, 0, stream>>>(hp16, esrc, offs, deg, perm, hm16, nN);
    sage_gemm_mfma<64, 2, false, true><<<mgrid, 256, 0, stream>>>(hp16, hm16, ws2, wn2, b2, out, nullptr, nN);
}

// Round 15
// 213.341 us; speedup vs baseline: 1.5961x; 1.5961x over previous
//
#include <hip/hip_runtime.h>
#include <hip/hip_fp16.h>

// GraphSAGE 3-layer forward, f32 output.
// CSR build: 6-kernel chain (degree-sort perm REVERTED: 50k atomics on 64
// bins serialized at 133us; gather proved memory-bound, not divergence-bound).
// init: fused zero+tof16. Gather: thread-per-(node,octet), 4x edge unroll,
// fp16->fp16 (at random-row L3/HBM roofline ~28us/layer). GEMM: direct fp16
// MFMA, 128-thr blocks (391 blocks -> full CU coverage), weights in LDS;
// h-planes fp16-only (in-place rotating); final layer writes f32.

#define DIN 96

typedef __attribute__((ext_vector_type(8))) _Float16 f16x8;
typedef __attribute__((ext_vector_type(16))) float f32x16;

// ---- fused init: zero deg + f32->fp16 input plane ----
__global__ void init_kernel(const float* __restrict__ x, __half* __restrict__ xf,
                            int* __restrict__ deg, int nN, int n8) {
    int i = blockIdx.x * blockDim.x + threadIdx.x;
    if (i < nN) deg[i] = 0;
    if (i >= n8) return;
    float4 f0 = *reinterpret_cast<const float4*>(x + (size_t)i * 8);
    float4 f1 = *reinterpret_cast<const float4*>(x + (size_t)i * 8 + 4);
    union { __half2 h2[4]; float4 raw; } o;
    o.h2[0] = __float22half2_rn(make_float2(f0.x, f0.y));
    o.h2[1] = __float22half2_rn(make_float2(f0.z, f0.w));
    o.h2[2] = __float22half2_rn(make_float2(f1.x, f1.y));
    o.h2[3] = __float22half2_rn(make_float2(f1.z, f1.w));
    *reinterpret_cast<float4*>(xf + (size_t)i * 8) = o.raw;
}

// ---- degree histogram + per-edge rank ----
__global__ void deg_kernel(const int* __restrict__ dst, int* __restrict__ deg,
                           int* __restrict__ rank, int nE) {
    int i = blockIdx.x * blockDim.x + threadIdx.x;
    if (i < nE) rank[i] = atomicAdd(&deg[dst[i]], 1);
}

// ---- hierarchical exclusive scan, phase 1: per-block sums ----
__global__ void block_sum_kernel(const int* __restrict__ deg, int* __restrict__ bsum, int nN) {
    __shared__ int s[256];
    const int tid = threadIdx.x;
    int i = blockIdx.x * 256 + tid;
    s[tid] = (i < nN) ? deg[i] : 0;
    __syncthreads();
    for (int d = 128; d > 0; d >>= 1) {
        if (tid < d) s[tid] += s[tid + d];
        __syncthreads();
    }
    if (tid == 0) bsum[blockIdx.x] = s[0];
}

// ---- phase 2: exclusive scan of block sums ----
__global__ void bsum_scan_kernel(int* __restrict__ bsum, int nB) {
    __shared__ int s[256];
    const int tid = threadIdx.x;
    int v = (tid < nB) ? bsum[tid] : 0;
    s[tid] = v;
    __syncthreads();
    for (int d = 1; d < 256; d <<= 1) {
        int t = (tid >= d) ? s[tid - d] : 0;
        __syncthreads();
        s[tid] += t;
        __syncthreads();
    }
    if (tid < nB) bsum[tid] = s[tid] - v;   // exclusive
}

// ---- phase 3: local exclusive scan + block base -> offs ----
__global__ void scan_apply_kernel(const int* __restrict__ deg, const int* __restrict__ bsum,
                                  int* __restrict__ offs, int nN) {
    __shared__ int s[256];
    const int tid = threadIdx.x;
    int i = blockIdx.x * 256 + tid;
    int v = (i < nN) ? deg[i] : 0;
    s[tid] = v;
    __syncthreads();
    for (int d = 1; d < 256; d <<= 1) {
        int t = (tid >= d) ? s[tid - d] : 0;
        __syncthreads();
        s[tid] += t;
        __syncthreads();
    }
    if (i < nN) offs[i] = bsum[blockIdx.x] + s[tid] - v;
}

// ---- bucket fill (atomic-free) ----
__global__ void bucket_kernel(const int* __restrict__ src, const int* __restrict__ dst,
                              const int* __restrict__ offs, const int* __restrict__ rank,
                              unsigned short* __restrict__ esrc, int nE) {
    int e = blockIdx.x * blockDim.x + threadIdx.x;
    if (e < nE) esrc[offs[dst[e]] + rank[e]] = (unsigned short)src[e];
}

// ---- gather: thread = (node, octet of 8 halves); 12 threads/node; 4x unroll ----
__global__ void gather_kernel(const __half* __restrict__ hf, const unsigned short* __restrict__ esrc,
                              const int* __restrict__ offs, const int* __restrict__ deg,
                              __half* __restrict__ hmean, int nN) {
    int idx = blockIdx.x * blockDim.x + threadIdx.x;
    if (idx >= nN * 12) return;
    int n = idx / 12;
    int q = idx - n * 12;
    const int beg = offs[n];
    const int dg = deg[n];
    const int end = beg + dg;
    const __half* hq = hf + q * 8;

    union H8 { float4 raw; __half2 h2[4]; };
    float a0[8], a1[8], a2[8], a3[8];
#pragma unroll
    for (int k = 0; k < 8; ++k) { a0[k] = 0.f; a1[k] = 0.f; a2[k] = 0.f; a3[k] = 0.f; }

    int j = beg;
    for (; j + 4 <= end; j += 4) {
        int s0 = esrc[j], s1 = esrc[j + 1], s2 = esrc[j + 2], s3 = esrc[j + 3];
        H8 v0, v1, v2, v3;
        v0.raw = *reinterpret_cast<const float4*>(hq + (size_t)s0 * DIN);
        v1.raw = *reinterpret_cast<const float4*>(hq + (size_t)s1 * DIN);
        v2.raw = *reinterpret_cast<const float4*>(hq + (size_t)s2 * DIN);
        v3.raw = *reinterpret_cast<const float4*>(hq + (size_t)s3 * DIN);
#pragma unroll
        for (int k = 0; k < 4; ++k) {
            float2 f0 = __half22float2(v0.h2[k]);
            float2 f1 = __half22float2(v1.h2[k]);
            float2 f2 = __half22float2(v2.h2[k]);
            float2 f3 = __half22float2(v3.h2[k]);
            a0[2 * k] += f0.x; a0[2 * k + 1] += f0.y;
            a1[2 * k] += f1.x; a1[2 * k + 1] += f1.y;
            a2[2 * k] += f2.x; a2[2 * k + 1] += f2.y;
            a3[2 * k] += f3.x; a3[2 * k + 1] += f3.y;
        }
    }
    for (; j < end; ++j) {
        int s0 = esrc[j];
        H8 v0;
        v0.raw = *reinterpret_cast<const float4*>(hq + (size_t)s0 * DIN);
#pragma unroll
        for (int k = 0; k < 4; ++k) {
            float2 f0 = __half22float2(v0.h2[k]);
            a0[2 * k] += f0.x; a0[2 * k + 1] += f0.y;
        }
    }
    const float r = 1.0f / (float)max(dg, 1);
    union H8 o;
    o.h2[0] = __float22half2_rn(make_float2((a0[0]+a1[0]+a2[0]+a3[0])*r, (a0[1]+a1[1]+a2[1]+a3[1])*r));
    o.h2[1] = __float22half2_rn(make_float2((a0[2]+a1[2]+a2[2]+a3[2])*r, (a0[3]+a1[3]+a2[3]+a3[3])*r));
    o.h2[2] = __float22half2_rn(make_float2((a0[4]+a1[4]+a2[4]+a3[4])*r, (a0[5]+a1[5]+a2[5]+a3[5])*r));
    o.h2[3] = __float22half2_rn(make_float2((a0[6]+a1[6]+a2[6]+a3[6])*r, (a0[7]+a1[7]+a2[7]+a3[7])*r));
    *reinterpret_cast<float4*>(hmean + (size_t)n * DIN + q * 8) = o.raw;
}

// ---- fused SAGE layer GEMM: direct fp16 MFMA ----
// Block: 128 thr = 2 waves x 64 nodes (grid 391 -> full CU coverage, 4
// blocks/CU by LDS); ALL DOUT cols per block; weights fp16 in LDS. Per ks:
// 2 A-frag b128 loads, NP weight b128 LDS reads, NP*2 MFMA. FINAL=false:
// fp16 in-place epilogue (wave-private rows, reads-before-writes); else f32.
template<int DOUT, int NP, bool RELU, bool FINAL>
__global__ __launch_bounds__(128)
void sage_gemm_mfma(const __half* __restrict__ hp, const __half* __restrict__ hm,
                    const float* __restrict__ wself, const float* __restrict__ wneigh,
                    const float* __restrict__ bias, float* __restrict__ fout,
                    __half* __restrict__ hout, int nN) {
    __shared__ unsigned int WS[DOUT][100];   // 200 fp16 per row (192 + pad)

    const int tid = threadIdx.x;
    const int n0 = blockIdx.x * 128;

    // stage full weight matrix W' = [Wself | Wneigh] as fp16
    for (int c = tid; c < DOUT * 24; c += 128) {
        int r = c / 24, k8 = c - (c / 24) * 24;
        const float* srcw = (k8 < 12) ? (wself + (size_t)r * 96 + k8 * 8)
                                      : (wneigh + (size_t)r * 96 + (k8 - 12) * 8);
        float4 f0 = *reinterpret_cast<const float4*>(srcw);
        float4 f1 = *reinterpret_cast<const float4*>(srcw + 4);
        union { __half2 h2[4]; unsigned int u[4]; } o;
        o.h2[0] = __float22half2_rn(make_float2(f0.x, f0.y));
        o.h2[1] = __float22half2_rn(make_float2(f0.z, f0.w));
        o.h2[2] = __float22half2_rn(make_float2(f1.x, f1.y));
        o.h2[3] = __float22half2_rn(make_float2(f1.z, f1.w));
        WS[r][k8 * 4 + 0] = o.u[0];
        WS[r][k8 * 4 + 1] = o.u[1];
        WS[r][k8 * 4 + 2] = o.u[2];
        WS[r][k8 * 4 + 3] = o.u[3];
    }
    __syncthreads();

    const int lane = tid & 63;
    const int w = tid >> 6;           // wave 0..1
    const int col = lane & 31;
    const int q = lane >> 5;
    const int mbase = n0 + w * 64;

    const int nA0 = min(mbase + col, nN - 1);
    const int nA1 = min(mbase + 32 + col, nN - 1);

    f32x16 acc[NP][2];
#pragma unroll
    for (int p = 0; p < NP; ++p) {
        f32x16 z = {};
        acc[p][0] = z;
        acc[p][1] = z;
    }

#pragma unroll
    for (int ks = 0; ks < 12; ++ks) {
        const __half* s0 = (ks < 6) ? (hp + (size_t)nA0 * 96 + ks * 16 + q * 8)
                                    : (hm + (size_t)nA0 * 96 + (ks - 6) * 16 + q * 8);
        const __half* s1 = (ks < 6) ? (hp + (size_t)nA1 * 96 + ks * 16 + q * 8)
                                    : (hm + (size_t)nA1 * 96 + (ks - 6) * 16 + q * 8);
        union { float4 raw; f16x8 v; } a0, a1;
        a0.raw = *reinterpret_cast<const float4*>(s0);
        a1.raw = *reinterpret_cast<const float4*>(s1);

#pragma unroll
        for (int p = 0; p < NP; ++p) {
            const f16x8 wv = *reinterpret_cast<const f16x8*>(&WS[p * 32 + col][ks * 8 + q * 4]);
            acc[p][0] = __builtin_amdgcn_mfma_f32_32x32x16_f16(a0.v, wv, acc[p][0], 0, 0, 0);
            acc[p][1] = __builtin_amdgcn_mfma_f32_32x32x16_f16(a1.v, wv, acc[p][1], 0, 0, 0);
        }
    }

    // epilogue: C/D layout col=lane&31, row=(i&3)+8*(i>>2)+4*q
#pragma unroll
    for (int p = 0; p < NP; ++p) {
        const int oc = p * 32 + col;
        const float bv = bias[oc];
#pragma unroll
        for (int i = 0; i < 16; ++i) {
            const int row = (i & 3) + 8 * (i >> 2) + 4 * q;
            int n = mbase + row;
            if (n < nN) {
                float v = acc[p][0][i] + bv;
                if (RELU) v = fmaxf(v, 0.f);
                if (FINAL) fout[(size_t)n * DOUT + oc] = v;
                else       hout[(size_t)n * DOUT + oc] = __float2half_rn(v);
            }
            n = mbase + 32 + row;
            if (n < nN) {
                float v = acc[p][1][i] + bv;
                if (RELU) v = fmaxf(v, 0.f);
                if (FINAL) fout[(size_t)n * DOUT + oc] = v;
                else       hout[(size_t)n * DOUT + oc] = __float2half_rn(v);
            }
        }
    }
}

extern "C" void kernel_launch(void* const* d_in, const int* in_sizes, int n_in,
                              void* d_out, int out_size, void* d_ws, size_t ws_size,
                              hipStream_t stream) {
    const float* x   = (const float*)d_in[0];
    const int*   src = (const int*)d_in[1];
    const int*   dst = (const int*)d_in[2];
    const float* ws0 = (const float*)d_in[3];
    const float* wn0 = (const float*)d_in[4];
    const float* b0  = (const float*)d_in[5];
    const float* ws1 = (const float*)d_in[6];
    const float* wn1 = (const float*)d_in[7];
    const float* b1  = (const float*)d_in[8];
    const float* ws2 = (const float*)d_in[9];
    const float* wn2 = (const float*)d_in[10];
    const float* b2  = (const float*)d_in[11];
    float* out = (float*)d_out;

    const int nN = in_sizes[0] / DIN;   // 50000
    const int nE = in_sizes[1];         // 800000
    const int nB = (nN + 255) / 256;    // scan blocks
    const int n8 = nN * 12;

    // workspace: deg[50048] offs[50048] bsum[256] rank[nE] (int)
    //            | esrc[nE] (ushort) | hp16[nN*96] (f16) | hm16[nN*96] (f16)
    int* deg  = (int*)d_ws;
    int* offs = deg + 50048;
    int* bsum = offs + 50048;
    int* rank = bsum + 256;
    unsigned short* esrc = (unsigned short*)(rank + nE);
    __half* hp16 = (__half*)(esrc + nE);       // rotating h plane (in-place)
    __half* hm16 = hp16 + (size_t)nN * DIN;    // gather output

    // ---- fused init (zero deg + tof16) ----
    init_kernel<<<(n8 + 255) / 256, 256, 0, stream>>>(x, hp16, deg, nN, n8);

    // ---- build CSR by dst ----
    deg_kernel<<<(nE + 255) / 256, 256, 0, stream>>>(dst, deg, rank, nE);
    block_sum_kernel<<<nB, 256, 0, stream>>>(deg, bsum, nN);
    bsum_scan_kernel<<<1, 256, 0, stream>>>(bsum, nB);
    scan_apply_kernel<<<nB, 256, 0, stream>>>(deg, bsum, offs, nN);
    bucket_kernel<<<(nE + 255) / 256, 256, 0, stream>>>(src, dst, offs, rank, esrc, nE);

    const int ggrid = (nN * 12 + 255) / 256;
    const int mgrid = (nN + 127) / 128;    // 391 GEMM blocks, 128 thr each

    // ---- layer 0 ----
    gather_kernel<<<ggrid, 256, 0, stream>>>(hp16, esrc, offs, deg, hm16, nN);
    sage_gemm_mfma<96, 3, true, false><<<mgrid, 128, 0, stream>>>(hp16, hm16, ws0, wn0, b0, nullptr, hp16, nN);

    // ---- layer 1 ----
    gather_kernel<<<ggrid, 256, 0, stream>>>(hp16, esrc, offs, deg, hm16, nN);
    sage_gemm_mfma<96, 3, true, false><<<mgrid, 128, 0, stream>>>(hp16, hm16, ws1, wn1, b1, nullptr, hp16, nN);

    // ---- layer 2 ----
    gather_kernel<<<ggrid, 256, 0, stream>>>(hp16, esrc, offs, deg, hm16, nN);
    sage_gemm_mfma<64, 2, false, true><<<mgrid, 128, 0, stream>>>(hp16, hm16, ws2, wn2, b2, out, nullptr, nN);
}

// Round 16
// 209.500 us; speedup vs baseline: 1.6253x; 1.0183x over previous
//
#include <hip/hip_runtime.h>
#include <hip/hip_fp16.h>

// GraphSAGE 3-layer forward, f32 output.
// CSR build: 6-kernel chain. init: fused zero+tof16. Gather: thread-per-
// (node,octet), 8-deep edge MLP unroll (latency-vs-BW probe; acc order
// preserved -> bit-identical absmax), fp16->fp16. GEMM: direct fp16 MFMA,
// 128-thr blocks, weights in LDS; h-planes fp16-only (in-place rotating);
// final layer writes f32.

#define DIN 96

typedef __attribute__((ext_vector_type(8))) _Float16 f16x8;
typedef __attribute__((ext_vector_type(16))) float f32x16;

// ---- fused init: zero deg + f32->fp16 input plane ----
__global__ void init_kernel(const float* __restrict__ x, __half* __restrict__ xf,
                            int* __restrict__ deg, int nN, int n8) {
    int i = blockIdx.x * blockDim.x + threadIdx.x;
    if (i < nN) deg[i] = 0;
    if (i >= n8) return;
    float4 f0 = *reinterpret_cast<const float4*>(x + (size_t)i * 8);
    float4 f1 = *reinterpret_cast<const float4*>(x + (size_t)i * 8 + 4);
    union { __half2 h2[4]; float4 raw; } o;
    o.h2[0] = __float22half2_rn(make_float2(f0.x, f0.y));
    o.h2[1] = __float22half2_rn(make_float2(f0.z, f0.w));
    o.h2[2] = __float22half2_rn(make_float2(f1.x, f1.y));
    o.h2[3] = __float22half2_rn(make_float2(f1.z, f1.w));
    *reinterpret_cast<float4*>(xf + (size_t)i * 8) = o.raw;
}

// ---- degree histogram + per-edge rank ----
__global__ void deg_kernel(const int* __restrict__ dst, int* __restrict__ deg,
                           int* __restrict__ rank, int nE) {
    int i = blockIdx.x * blockDim.x + threadIdx.x;
    if (i < nE) rank[i] = atomicAdd(&deg[dst[i]], 1);
}

// ---- hierarchical exclusive scan, phase 1: per-block sums ----
__global__ void block_sum_kernel(const int* __restrict__ deg, int* __restrict__ bsum, int nN) {
    __shared__ int s[256];
    const int tid = threadIdx.x;
    int i = blockIdx.x * 256 + tid;
    s[tid] = (i < nN) ? deg[i] : 0;
    __syncthreads();
    for (int d = 128; d > 0; d >>= 1) {
        if (tid < d) s[tid] += s[tid + d];
        __syncthreads();
    }
    if (tid == 0) bsum[blockIdx.x] = s[0];
}

// ---- phase 2: exclusive scan of block sums ----
__global__ void bsum_scan_kernel(int* __restrict__ bsum, int nB) {
    __shared__ int s[256];
    const int tid = threadIdx.x;
    int v = (tid < nB) ? bsum[tid] : 0;
    s[tid] = v;
    __syncthreads();
    for (int d = 1; d < 256; d <<= 1) {
        int t = (tid >= d) ? s[tid - d] : 0;
        __syncthreads();
        s[tid] += t;
        __syncthreads();
    }
    if (tid < nB) bsum[tid] = s[tid] - v;   // exclusive
}

// ---- phase 3: local exclusive scan + block base -> offs ----
__global__ void scan_apply_kernel(const int* __restrict__ deg, const int* __restrict__ bsum,
                                  int* __restrict__ offs, int nN) {
    __shared__ int s[256];
    const int tid = threadIdx.x;
    int i = blockIdx.x * 256 + tid;
    int v = (i < nN) ? deg[i] : 0;
    s[tid] = v;
    __syncthreads();
    for (int d = 1; d < 256; d <<= 1) {
        int t = (tid >= d) ? s[tid - d] : 0;
        __syncthreads();
        s[tid] += t;
        __syncthreads();
    }
    if (i < nN) offs[i] = bsum[blockIdx.x] + s[tid] - v;
}

// ---- bucket fill (atomic-free) ----
__global__ void bucket_kernel(const int* __restrict__ src, const int* __restrict__ dst,
                              const int* __restrict__ offs, const int* __restrict__ rank,
                              unsigned short* __restrict__ esrc, int nE) {
    int e = blockIdx.x * blockDim.x + threadIdx.x;
    if (e < nE) esrc[offs[dst[e]] + rank[e]] = (unsigned short)src[e];
}

// ---- gather: thread = (node, octet); 12 threads/node; 8-deep MLP unroll ----
__global__ void gather_kernel(const __half* __restrict__ hf, const unsigned short* __restrict__ esrc,
                              const int* __restrict__ offs, const int* __restrict__ deg,
                              __half* __restrict__ hmean, int nN) {
    int idx = blockIdx.x * blockDim.x + threadIdx.x;
    if (idx >= nN * 12) return;
    int n = idx / 12;
    int q = idx - n * 12;
    const int beg = offs[n];
    const int dg = deg[n];
    const int end = beg + dg;
    const __half* hq = hf + q * 8;

    union H8 { float4 raw; __half2 h2[4]; };
    float a0[8], a1[8], a2[8], a3[8];
#pragma unroll
    for (int k = 0; k < 8; ++k) { a0[k] = 0.f; a1[k] = 0.f; a2[k] = 0.f; a3[k] = 0.f; }

    int j = beg;
    // 8-deep: 8 independent row loads in flight; acc assignment matches the
    // 4-unroll exactly (a_i gets edges j+i then j+4+i, sequential adds).
    for (; j + 8 <= end; j += 8) {
        int s0 = esrc[j],     s1 = esrc[j + 1], s2 = esrc[j + 2], s3 = esrc[j + 3];
        int s4 = esrc[j + 4], s5 = esrc[j + 5], s6 = esrc[j + 6], s7 = esrc[j + 7];
        H8 v0, v1, v2, v3, v4, v5, v6, v7;
        v0.raw = *reinterpret_cast<const float4*>(hq + (size_t)s0 * DIN);
        v1.raw = *reinterpret_cast<const float4*>(hq + (size_t)s1 * DIN);
        v2.raw = *reinterpret_cast<const float4*>(hq + (size_t)s2 * DIN);
        v3.raw = *reinterpret_cast<const float4*>(hq + (size_t)s3 * DIN);
        v4.raw = *reinterpret_cast<const float4*>(hq + (size_t)s4 * DIN);
        v5.raw = *reinterpret_cast<const float4*>(hq + (size_t)s5 * DIN);
        v6.raw = *reinterpret_cast<const float4*>(hq + (size_t)s6 * DIN);
        v7.raw = *reinterpret_cast<const float4*>(hq + (size_t)s7 * DIN);
#pragma unroll
        for (int k = 0; k < 4; ++k) {
            float2 f0 = __half22float2(v0.h2[k]);
            float2 f1 = __half22float2(v1.h2[k]);
            float2 f2 = __half22float2(v2.h2[k]);
            float2 f3 = __half22float2(v3.h2[k]);
            a0[2 * k] += f0.x; a0[2 * k + 1] += f0.y;
            a1[2 * k] += f1.x; a1[2 * k + 1] += f1.y;
            a2[2 * k] += f2.x; a2[2 * k + 1] += f2.y;
            a3[2 * k] += f3.x; a3[2 * k + 1] += f3.y;
        }
#pragma unroll
        for (int k = 0; k < 4; ++k) {
            float2 f4 = __half22float2(v4.h2[k]);
            float2 f5 = __half22float2(v5.h2[k]);
            float2 f6 = __half22float2(v6.h2[k]);
            float2 f7 = __half22float2(v7.h2[k]);
            a0[2 * k] += f4.x; a0[2 * k + 1] += f4.y;
            a1[2 * k] += f5.x; a1[2 * k + 1] += f5.y;
            a2[2 * k] += f6.x; a2[2 * k + 1] += f6.y;
            a3[2 * k] += f7.x; a3[2 * k + 1] += f7.y;
        }
    }
    for (; j + 4 <= end; j += 4) {
        int s0 = esrc[j], s1 = esrc[j + 1], s2 = esrc[j + 2], s3 = esrc[j + 3];
        H8 v0, v1, v2, v3;
        v0.raw = *reinterpret_cast<const float4*>(hq + (size_t)s0 * DIN);
        v1.raw = *reinterpret_cast<const float4*>(hq + (size_t)s1 * DIN);
        v2.raw = *reinterpret_cast<const float4*>(hq + (size_t)s2 * DIN);
        v3.raw = *reinterpret_cast<const float4*>(hq + (size_t)s3 * DIN);
#pragma unroll
        for (int k = 0; k < 4; ++k) {
            float2 f0 = __half22float2(v0.h2[k]);
            float2 f1 = __half22float2(v1.h2[k]);
            float2 f2 = __half22float2(v2.h2[k]);
            float2 f3 = __half22float2(v3.h2[k]);
            a0[2 * k] += f0.x; a0[2 * k + 1] += f0.y;
            a1[2 * k] += f1.x; a1[2 * k + 1] += f1.y;
            a2[2 * k] += f2.x; a2[2 * k + 1] += f2.y;
            a3[2 * k] += f3.x; a3[2 * k + 1] += f3.y;
        }
    }
    for (; j < end; ++j) {
        int s0 = esrc[j];
        H8 v0;
        v0.raw = *reinterpret_cast<const float4*>(hq + (size_t)s0 * DIN);
#pragma unroll
        for (int k = 0; k < 4; ++k) {
            float2 f0 = __half22float2(v0.h2[k]);
            a0[2 * k] += f0.x; a0[2 * k + 1] += f0.y;
        }
    }
    const float r = 1.0f / (float)max(dg, 1);
    union H8 o;
    o.h2[0] = __float22half2_rn(make_float2((a0[0]+a1[0]+a2[0]+a3[0])*r, (a0[1]+a1[1]+a2[1]+a3[1])*r));
    o.h2[1] = __float22half2_rn(make_float2((a0[2]+a1[2]+a2[2]+a3[2])*r, (a0[3]+a1[3]+a2[3]+a3[3])*r));
    o.h2[2] = __float22half2_rn(make_float2((a0[4]+a1[4]+a2[4]+a3[4])*r, (a0[5]+a1[5]+a2[5]+a3[5])*r));
    o.h2[3] = __float22half2_rn(make_float2((a0[6]+a1[6]+a2[6]+a3[6])*r, (a0[7]+a1[7]+a2[7]+a3[7])*r));
    *reinterpret_cast<float4*>(hmean + (size_t)n * DIN + q * 8) = o.raw;
}

// ---- fused SAGE layer GEMM: direct fp16 MFMA ----
// Block: 128 thr = 2 waves x 64 nodes; ALL DOUT cols per block; weights fp16
// in LDS. FINAL=false: fp16 in-place epilogue (wave-private rows); else f32.
template<int DOUT, int NP, bool RELU, bool FINAL>
__global__ __launch_bounds__(128)
void sage_gemm_mfma(const __half* __restrict__ hp, const __half* __restrict__ hm,
                    const float* __restrict__ wself, const float* __restrict__ wneigh,
                    const float* __restrict__ bias, float* __restrict__ fout,
                    __half* __restrict__ hout, int nN) {
    __shared__ unsigned int WS[DOUT][100];   // 200 fp16 per row (192 + pad)

    const int tid = threadIdx.x;
    const int n0 = blockIdx.x * 128;

    for (int c = tid; c < DOUT * 24; c += 128) {
        int r = c / 24, k8 = c - (c / 24) * 24;
        const float* srcw = (k8 < 12) ? (wself + (size_t)r * 96 + k8 * 8)
                                      : (wneigh + (size_t)r * 96 + (k8 - 12) * 8);
        float4 f0 = *reinterpret_cast<const float4*>(srcw);
        float4 f1 = *reinterpret_cast<const float4*>(srcw + 4);
        union { __half2 h2[4]; unsigned int u[4]; } o;
        o.h2[0] = __float22half2_rn(make_float2(f0.x, f0.y));
        o.h2[1] = __float22half2_rn(make_float2(f0.z, f0.w));
        o.h2[2] = __float22half2_rn(make_float2(f1.x, f1.y));
        o.h2[3] = __float22half2_rn(make_float2(f1.z, f1.w));
        WS[r][k8 * 4 + 0] = o.u[0];
        WS[r][k8 * 4 + 1] = o.u[1];
        WS[r][k8 * 4 + 2] = o.u[2];
        WS[r][k8 * 4 + 3] = o.u[3];
    }
    __syncthreads();

    const int lane = tid & 63;
    const int w = tid >> 6;           // wave 0..1
    const int col = lane & 31;
    const int q = lane >> 5;
    const int mbase = n0 + w * 64;

    const int nA0 = min(mbase + col, nN - 1);
    const int nA1 = min(mbase + 32 + col, nN - 1);

    f32x16 acc[NP][2];
#pragma unroll
    for (int p = 0; p < NP; ++p) {
        f32x16 z = {};
        acc[p][0] = z;
        acc[p][1] = z;
    }

#pragma unroll
    for (int ks = 0; ks < 12; ++ks) {
        const __half* s0 = (ks < 6) ? (hp + (size_t)nA0 * 96 + ks * 16 + q * 8)
                                    : (hm + (size_t)nA0 * 96 + (ks - 6) * 16 + q * 8);
        const __half* s1 = (ks < 6) ? (hp + (size_t)nA1 * 96 + ks * 16 + q * 8)
                                    : (hm + (size_t)nA1 * 96 + (ks - 6) * 16 + q * 8);
        union { float4 raw; f16x8 v; } a0, a1;
        a0.raw = *reinterpret_cast<const float4*>(s0);
        a1.raw = *reinterpret_cast<const float4*>(s1);

#pragma unroll
        for (int p = 0; p < NP; ++p) {
            const f16x8 wv = *reinterpret_cast<const f16x8*>(&WS[p * 32 + col][ks * 8 + q * 4]);
            acc[p][0] = __builtin_amdgcn_mfma_f32_32x32x16_f16(a0.v, wv, acc[p][0], 0, 0, 0);
            acc[p][1] = __builtin_amdgcn_mfma_f32_32x32x16_f16(a1.v, wv, acc[p][1], 0, 0, 0);
        }
    }

    // epilogue: C/D layout col=lane&31, row=(i&3)+8*(i>>2)+4*q
#pragma unroll
    for (int p = 0; p < NP; ++p) {
        const int oc = p * 32 + col;
        const float bv = bias[oc];
#pragma unroll
        for (int i = 0; i < 16; ++i) {
            const int row = (i & 3) + 8 * (i >> 2) + 4 * q;
            int n = mbase + row;
            if (n < nN) {
                float v = acc[p][0][i] + bv;
                if (RELU) v = fmaxf(v, 0.f);
                if (FINAL) fout[(size_t)n * DOUT + oc] = v;
                else       hout[(size_t)n * DOUT + oc] = __float2half_rn(v);
            }
            n = mbase + 32 + row;
            if (n < nN) {
                float v = acc[p][1][i] + bv;
                if (RELU) v = fmaxf(v, 0.f);
                if (FINAL) fout[(size_t)n * DOUT + oc] = v;
                else       hout[(size_t)n * DOUT + oc] = __float2half_rn(v);
            }
        }
    }
}

extern "C" void kernel_launch(void* const* d_in, const int* in_sizes, int n_in,
                              void* d_out, int out_size, void* d_ws, size_t ws_size,
                              hipStream_t stream) {
    const float* x   = (const float*)d_in[0];
    const int*   src = (const int*)d_in[1];
    const int*   dst = (const int*)d_in[2];
    const float* ws0 = (const float*)d_in[3];
    const float* wn0 = (const float*)d_in[4];
    const float* b0  = (const float*)d_in[5];
    const float* ws1 = (const float*)d_in[6];
    const float* wn1 = (const float*)d_in[7];
    const float* b1  = (const float*)d_in[8];
    const float* ws2 = (const float*)d_in[9];
    const float* wn2 = (const float*)d_in[10];
    const float* b2  = (const float*)d_in[11];
    float* out = (float*)d_out;

    const int nN = in_sizes[0] / DIN;   // 50000
    const int nE = in_sizes[1];         // 800000
    const int nB = (nN + 255) / 256;    // scan blocks
    const int n8 = nN * 12;

    // workspace: deg[50048] offs[50048] bsum[256] rank[nE] (int)
    //            | esrc[nE] (ushort) | hp16[nN*96] (f16) | hm16[nN*96] (f16)
    int* deg  = (int*)d_ws;
    int* offs = deg + 50048;
    int* bsum = offs + 50048;
    int* rank = bsum + 256;
    unsigned short* esrc = (unsigned short*)(rank + nE);
    __half* hp16 = (__half*)(esrc + nE);       // rotating h plane (in-place)
    __half* hm16 = hp16 + (size_t)nN * DIN;    // gather output

    // ---- fused init (zero deg + tof16) ----
    init_kernel<<<(n8 + 255) / 256, 256, 0, stream>>>(x, hp16, deg, nN, n8);

    // ---- build CSR by dst ----
    deg_kernel<<<(nE + 255) / 256, 256, 0, stream>>>(dst, deg, rank, nE);
    block_sum_kernel<<<nB, 256, 0, stream>>>(deg, bsum, nN);
    bsum_scan_kernel<<<1, 256, 0, stream>>>(bsum, nB);
    scan_apply_kernel<<<nB, 256, 0, stream>>>(deg, bsum, offs, nN);
    bucket_kernel<<<(nE + 255) / 256, 256, 0, stream>>>(src, dst, offs, rank, esrc, nE);

    const int ggrid = (nN * 12 + 255) / 256;
    const int mgrid = (nN + 127) / 128;    // 391 GEMM blocks, 128 thr each

    // ---- layer 0 ----
    gather_kernel<<<ggrid, 256, 0, stream>>>(hp16, esrc, offs, deg, hm16, nN);
    sage_gemm_mfma<96, 3, true, false><<<mgrid, 128, 0, stream>>>(hp16, hm16, ws0, wn0, b0, nullptr, hp16, nN);

    // ---- layer 1 ----
    gather_kernel<<<ggrid, 256, 0, stream>>>(hp16, esrc, offs, deg, hm16, nN);
    sage_gemm_mfma<96, 3, true, false><<<mgrid, 128, 0, stream>>>(hp16, hm16, ws1, wn1, b1, nullptr, hp16, nN);

    // ---- layer 2 ----
    gather_kernel<<<ggrid, 256, 0, stream>>>(hp16, esrc, offs, deg, hm16, nN);
    sage_gemm_mfma<64, 2, false, true><<<mgrid, 128, 0, stream>>>(hp16, hm16, ws2, wn2, b2, out, nullptr, nN);
}